// Round 3
// baseline (346.679 us; speedup 1.0000x reference)
//
#include <hip/hip_runtime.h>
#include <hip/hip_bf16.h>

#define N_EDGES 1000000
#define HID 128
#define VOC 105

// ws layout (fp16 element offsets)
#define WSU_T   0                     // [105][128] T = emb@W_emb[0:128] + b_emb (permuted cols)
#define WSU_U   (VOC * HID)           // 13440 : [105][128] U = emb@W_emb[128:256]
#define WSU_W3  (2 * VOC * HID)       // 26880 : W3 B-frags, 16384 elems
#define WSU_WP  (WSU_W3 + 16384)      // 43264 : W_pair A-frags (swapped gemm), 4096 elems
#define WSU_TU  (2 * VOC * HID)       // T+U contiguous span (elems) = 26880
#define WSB_VI  ((WSU_WP + 4096) * 2) // byte offset 94720 : u8 vi[N_EDGES]
#define WSB_VJ  (WSB_VI + N_EDGES)    // u8 vj[N_EDGES]

typedef float    f32x4 __attribute__((ext_vector_type(4)));
typedef _Float16 f16x8 __attribute__((ext_vector_type(8)));

// ---------------- prep: tables + pre-packed fragments + vocab pre-gather ----------------
__global__ void prep_kernel(const int*   __restrict__ xv,
                            const int*   __restrict__ ii,
                            const int*   __restrict__ jj,
                            const float* __restrict__ emb_table,
                            const float* __restrict__ W_pair,
                            const float* __restrict__ b_pair,
                            const float* __restrict__ W_emb,
                            const float* __restrict__ b_emb,
                            char* __restrict__ wsb) {
    _Float16* ws = (_Float16*)wsb;
    int b = blockIdx.x, t = threadIdx.x;
    if (b < VOC) {
        // T[v][h] = emb[v]@W_emb[0:128,h] + b_emb[h];  U[v][h] = emb[v]@W_emb[128:256,h]
        int v = b, which = t >> 7, h = t & 127;
        const float* wr = W_emb + which * HID * HID;
        const float* ev = emb_table + v * HID;
        float acc = which ? 0.f : b_emb[h];
        for (int d = 0; d < HID; ++d) acc = fmaf(ev[d], wr[d * HID + h], acc);
        ws[(which ? WSU_U : WSU_T) + v * HID + h] = (_Float16)acc;
    } else if (b < VOC + 64) {
        // W3 B-frags with K-permutation (matches swapped-pair-GEMM output) and
        // N-permutation h_out(nf,c)=8c+nf.  idx = q*512 + lane*8 + t, q = ks*8+nf
        int idx = (b - VOC) * 256 + t;            // 0..16383
        int tt = idx & 7, lane = (idx >> 3) & 63, q = idx >> 9;
        int ks = q >> 3, nf = q & 7;
        int hl = 16 * (tt >> 2) + 4 * (lane >> 4) + (tt & 3);   // logical k within 32-block
        int k = 32 * ks + hl;
        int n = 8 * (lane & 15) + nf;                            // permuted out col
        ws[WSU_W3 + idx] = (_Float16)W_emb[(2 * HID + k) * HID + n];
    } else if (b < VOC + 64 + 16) {
        // W_pair^T A-frags (A2[h][k] = W_pair[k][h]), bias b_pair folded at k==16
        int idx = (b - VOC - 64) * 256 + t;       // 0..4095
        int tt = idx & 7, lane = (idx >> 3) & 63, hf = idx >> 9;
        int k = 8 * (lane >> 4) + tt;
        int h = 16 * hf + (lane & 15);
        float v = (k < 16) ? W_pair[k * HID + h] : (k == 16 ? b_pair[h] : 0.f);
        ws[WSU_WP + idx] = (_Float16)v;
    } else {
        // vocab pre-gather: vi[e] = x[i[e]], vj[e] = x[j[e]] as bytes (VOC=105<256)
        int e4 = ((b - VOC - 64 - 16) * 256 + t) * 4;
        if (e4 < N_EDGES) {
            int4 iv = *(const int4*)(ii + e4);
            int4 jv = *(const int4*)(jj + e4);
            unsigned int vi = (unsigned)xv[iv.x] | ((unsigned)xv[iv.y] << 8) |
                              ((unsigned)xv[iv.z] << 16) | ((unsigned)xv[iv.w] << 24);
            unsigned int vj = (unsigned)xv[jv.x] | ((unsigned)xv[jv.y] << 8) |
                              ((unsigned)xv[jv.z] << 16) | ((unsigned)xv[jv.w] << 24);
            *(unsigned int*)(wsb + WSB_VI + e4) = vi;
            *(unsigned int*)(wsb + WSB_VJ + e4) = vj;
        }
    }
}

__device__ __forceinline__ float silu_f(float x) {
    return x / (1.f + __expf(-x));
}

// ---------------- main: W3-in-registers, T/U in LDS, pipelined global loads ----------------
__global__ __launch_bounds__(256, 3) void edge_kernel(
    const float* __restrict__ pair_basis,
    const char*  __restrict__ wsb,
    float* __restrict__ out)
{
    __shared__ __align__(16) _Float16 sTU[WSU_TU];   // T,U : 53760 B -> 3 blocks/CU
    const _Float16* ws = (const _Float16*)wsb;
    const int tid = threadIdx.x;
    {   // stage T/U into LDS
        const uint4* src = (const uint4*)ws;
        uint4* dst = (uint4*)sTU;
        for (int c = tid; c < (WSU_TU * 2 / 16); c += 256) dst[c] = src[c];
    }
    const int lane = tid & 63;
    const int w    = tid >> 6;     // wave 0..3
    const int m    = lane & 15;
    const int g    = lane >> 4;

    // loop-invariant operands in registers: W_pair^T A-frags + W3 B-frags
    f16x8 wpf[8];
    #pragma unroll
    for (int hf = 0; hf < 8; ++hf)
        wpf[hf] = *(const f16x8*)(ws + WSU_WP + (hf * 64 + lane) * 8);
    f16x8 w3r[32];
    #pragma unroll
    for (int q = 0; q < 32; ++q)
        w3r[q] = *(const f16x8*)(ws + WSU_W3 + (q * 64 + lane) * 8);
    __syncthreads();

    const _Float16* sT  = sTU;
    const _Float16* sU  = sTU + WSU_U;
    const unsigned char* viB = (const unsigned char*)(wsb + WSB_VI);
    const unsigned char* vjB = (const unsigned char*)(wsb + WSB_VJ);

    const int ntiles = N_EDGES / 64;            // 15625, 64 edges per block-tile (16/wave)
    const int gstep  = (int)gridDim.x;

    int tile = blockIdx.x;
    if (tile >= ntiles) return;

    // ---- prefetch first tile ----
    f32x4 p0 = {0,0,0,0}, p1 = {0,0,0,0};
    unsigned int viq, vjq;
    {
        int e0 = tile * 64 + w * 16;
        if (g < 2) {
            const float* pr = pair_basis + (size_t)(e0 + m) * 16 + g * 8;
            p0 = *(const f32x4*)pr; p1 = *(const f32x4*)(pr + 4);
        }
        viq = *(const unsigned int*)(viB + e0 + 4 * g);
        vjq = *(const unsigned int*)(vjB + e0 + 4 * g);
    }

    while (true) {
        const int e0 = tile * 64 + w * 16;
        const int nt = tile + gstep;

        // ---- issue next tile's global loads early (hide HBM latency under compute) ----
        f32x4 q0 = {0,0,0,0}, q1 = {0,0,0,0};
        unsigned int nvi = 0, nvj = 0;
        if (nt < ntiles) {
            int ne0 = nt * 64 + w * 16;
            if (g < 2) {
                const float* pr = pair_basis + (size_t)(ne0 + m) * 16 + g * 8;
                q0 = *(const f32x4*)pr; q1 = *(const f32x4*)(pr + 4);
            }
            nvi = *(const unsigned int*)(viB + ne0 + 4 * g);
            nvj = *(const unsigned int*)(vjB + ne0 + 4 * g);
        }

        // ---- B2 frag: pair^T (lane (m,g) supplies pair[e0+m][8g..8g+7]; k=16 row == 1 bias)
        f16x8 b2 = {0, 0, 0, 0, 0, 0, 0, 0};
        if (g < 2) {
            b2[0] = (_Float16)p0[0]; b2[1] = (_Float16)p0[1];
            b2[2] = (_Float16)p0[2]; b2[3] = (_Float16)p0[3];
            b2[4] = (_Float16)p1[0]; b2[5] = (_Float16)p1[1];
            b2[6] = (_Float16)p1[2]; b2[7] = (_Float16)p1[3];
        } else if (g == 2) {
            b2[0] = (_Float16)1.0f;
        }

        // ---- swapped pair GEMM -> silu -> main-GEMM A-frags (all registers) ----
        f16x8 a2[4];
        const f32x4 zero = {0.f, 0.f, 0.f, 0.f};
        #pragma unroll
        for (int ks = 0; ks < 4; ++ks) {
            f32x4 dA = __builtin_amdgcn_mfma_f32_16x16x32_f16(wpf[2 * ks],     b2, zero, 0, 0, 0);
            f32x4 dB = __builtin_amdgcn_mfma_f32_16x16x32_f16(wpf[2 * ks + 1], b2, zero, 0, 0, 0);
            f16x8 t2;
            #pragma unroll
            for (int r = 0; r < 4; ++r) {
                t2[r]     = (_Float16)silu_f(dA[r]);
                t2[4 + r] = (_Float16)silu_f(dB[r]);
            }
            a2[ks] = t2;
        }

        // ---- C init: T[vi] + U[vj] (b_emb folded into T), vec8 LDS reads ----
        f32x4 acc[8];
        #pragma unroll
        for (int r = 0; r < 4; ++r) {
            int vi = (viq >> (8 * r)) & 0xff;
            int vj = (vjq >> (8 * r)) & 0xff;
            f16x8 tv = *(const f16x8*)(sT + vi * HID + 8 * m);
            f16x8 uv = *(const f16x8*)(sU + vj * HID + 8 * m);
            #pragma unroll
            for (int nf = 0; nf < 8; ++nf)
                acc[nf][r] = (float)tv[nf] + (float)uv[nf];
        }

        // ---- main GEMM: acc += pb @ W3 (register B-frags) ----
        #pragma unroll
        for (int ks = 0; ks < 4; ++ks) {
            #pragma unroll
            for (int nf = 0; nf < 8; ++nf)
                acc[nf] = __builtin_amdgcn_mfma_f32_16x16x32_f16(a2[ks], w3r[ks * 8 + nf], acc[nf], 0, 0, 0);
        }

        // ---- epilogue: silu + contiguous float4 stores (cols 8m..8m+7 per thread) ----
        #pragma unroll
        for (int r = 0; r < 4; ++r) {
            float* op = out + (size_t)(e0 + 4 * g + r) * HID + 8 * m;
            f32x4 o0, o1;
            #pragma unroll
            for (int nf = 0; nf < 4; ++nf) {
                o0[nf] = silu_f(acc[nf][r]);
                o1[nf] = silu_f(acc[4 + nf][r]);
            }
            *(f32x4*)op       = o0;
            *(f32x4*)(op + 4) = o1;
        }

        if (nt >= ntiles) break;
        tile = nt; p0 = q0; p1 = q1; viq = nvi; vjq = nvj;
    }
}

extern "C" void kernel_launch(void* const* d_in, const int* in_sizes, int n_in,
                              void* d_out, int out_size, void* d_ws, size_t ws_size,
                              hipStream_t stream) {
    const int*   x          = (const int*)d_in[0];
    const float* pair_basis = (const float*)d_in[1];
    const int*   ii         = (const int*)d_in[2];
    const int*   jj         = (const int*)d_in[3];
    const float* emb_table  = (const float*)d_in[4];
    const float* W_pair     = (const float*)d_in[5];
    const float* b_pair     = (const float*)d_in[6];
    const float* W_emb      = (const float*)d_in[7];
    const float* b_emb      = (const float*)d_in[8];
    char* wsb = (char*)d_ws;
    float* out = (float*)d_out;

    const int ngather = (N_EDGES + 1023) / 1024;              // 977 blocks, 4 edges/thread
    prep_kernel<<<VOC + 64 + 16 + ngather, 256, 0, stream>>>(
        x, ii, jj, emb_table, W_pair, b_pair, W_emb, b_emb, wsb);
    edge_kernel<<<768, 256, 0, stream>>>(pair_basis, wsb, out);
}

// Round 4
// 208.077 us; speedup vs baseline: 1.6661x; 1.6661x over previous
//
#include <hip/hip_runtime.h>
#include <hip/hip_bf16.h>

#define N_EDGES 1000000
#define HID 128
#define VOC 105

// ws layout (fp16 element offsets)
#define WSU_T   0                     // [105][128] T = emb@W_emb[0:128] + b_emb (permuted cols)
#define WSU_U   (VOC * HID)           // 13440 : [105][128] U = emb@W_emb[128:256]
#define WSU_W3  (2 * VOC * HID)       // 26880 : W3 B-frags, 16384 elems
#define WSU_WP  (WSU_W3 + 16384)      // 43264 : W_pair A-frags (swapped gemm), 4096 elems
#define WSU_TU  (2 * VOC * HID)       // T+U contiguous span (elems) = 26880
#define WSB_VI  ((WSU_WP + 4096) * 2) // byte offset 94720 : u8 vi[N_EDGES]
#define WSB_VJ  (WSB_VI + N_EDGES)    // u8 vj[N_EDGES]

typedef float    f32x4 __attribute__((ext_vector_type(4)));
typedef _Float16 f16x8 __attribute__((ext_vector_type(8)));

static __device__ __forceinline__ f16x8 as_f16x8(f32x4 v) {
    return __builtin_bit_cast(f16x8, v);
}

// ---------------- prep: tables + pre-packed fragments + vocab pre-gather ----------------
__global__ void prep_kernel(const int*   __restrict__ xv,
                            const int*   __restrict__ ii,
                            const int*   __restrict__ jj,
                            const float* __restrict__ emb_table,
                            const float* __restrict__ W_pair,
                            const float* __restrict__ b_pair,
                            const float* __restrict__ W_emb,
                            const float* __restrict__ b_emb,
                            char* __restrict__ wsb) {
    _Float16* ws = (_Float16*)wsb;
    int b = blockIdx.x, t = threadIdx.x;
    if (b < VOC) {
        // T[v][h] = emb[v]@W_emb[0:128,h] + b_emb[h];  U[v][h] = emb[v]@W_emb[128:256,h]
        int v = b, which = t >> 7, h = t & 127;
        const float* wr = W_emb + which * HID * HID;
        const float* ev = emb_table + v * HID;
        float acc = which ? 0.f : b_emb[h];
        for (int d = 0; d < HID; ++d) acc = fmaf(ev[d], wr[d * HID + h], acc);
        ws[(which ? WSU_U : WSU_T) + v * HID + h] = (_Float16)acc;
    } else if (b < VOC + 64) {
        // W3 B-frags with K-permutation (matches swapped-pair-GEMM output) and
        // N-permutation h_out(nf,c)=8c+nf.  idx = q*512 + lane*8 + t, q = ks*8+nf
        int idx = (b - VOC) * 256 + t;            // 0..16383
        int tt = idx & 7, lane = (idx >> 3) & 63, q = idx >> 9;
        int ks = q >> 3, nf = q & 7;
        int hl = 16 * (tt >> 2) + 4 * (lane >> 4) + (tt & 3);   // logical k within 32-block
        int k = 32 * ks + hl;
        int n = 8 * (lane & 15) + nf;                            // permuted out col
        ws[WSU_W3 + idx] = (_Float16)W_emb[(2 * HID + k) * HID + n];
    } else if (b < VOC + 64 + 16) {
        // W_pair^T A-frags (A2[h][k] = W_pair[k][h]), bias b_pair folded at k==16
        int idx = (b - VOC - 64) * 256 + t;       // 0..4095
        int tt = idx & 7, lane = (idx >> 3) & 63, hf = idx >> 9;
        int k = 8 * (lane >> 4) + tt;
        int h = 16 * hf + (lane & 15);
        float v = (k < 16) ? W_pair[k * HID + h] : (k == 16 ? b_pair[h] : 0.f);
        ws[WSU_WP + idx] = (_Float16)v;
    } else {
        // vocab pre-gather: vi[e] = x[i[e]], vj[e] = x[j[e]] as bytes (VOC=105<256)
        int e4 = ((b - VOC - 64 - 16) * 256 + t) * 4;
        if (e4 < N_EDGES) {
            int4 iv = *(const int4*)(ii + e4);
            int4 jv = *(const int4*)(jj + e4);
            unsigned int vi = (unsigned)xv[iv.x] | ((unsigned)xv[iv.y] << 8) |
                              ((unsigned)xv[iv.z] << 16) | ((unsigned)xv[iv.w] << 24);
            unsigned int vj = (unsigned)xv[jv.x] | ((unsigned)xv[jv.y] << 8) |
                              ((unsigned)xv[jv.z] << 16) | ((unsigned)xv[jv.w] << 24);
            *(unsigned int*)(wsb + WSB_VI + e4) = vi;
            *(unsigned int*)(wsb + WSB_VJ + e4) = vj;
        }
    }
}

__device__ __forceinline__ float silu_f(float x) {
    return x / (1.f + __expf(-x));
}

// ---------------- main: asm-pinned W3/WP in registers, T/U in LDS ----------------
__global__ __launch_bounds__(256, 2) void edge_kernel(
    const float* __restrict__ pair_basis,
    const char*  __restrict__ wsb,
    float* __restrict__ out)
{
    __shared__ __align__(16) _Float16 sTU[WSU_TU];   // T,U : 53760 B
    const _Float16* ws = (const _Float16*)wsb;
    const int tid = threadIdx.x;
    {   // stage T/U into LDS
        const uint4* src = (const uint4*)ws;
        uint4* dst = (uint4*)sTU;
        for (int c = tid; c < (WSU_TU * 2 / 16); c += 256) dst[c] = src[c];
    }
    const int lane = tid & 63;
    const int w    = tid >> 6;     // wave 0..3
    const int m    = lane & 15;
    const int g    = lane >> 4;

    // loop-invariant operands, PINNED in registers via opaque asm (compiler
    // rematerialized these in-loop at VGPR=84 in R3 -> 775 MB HBM re-fetch)
    f32x4 wpf[8];
    #pragma unroll
    for (int hf = 0; hf < 8; ++hf)
        wpf[hf] = *(const f32x4*)(ws + WSU_WP + (hf * 64 + lane) * 8);
    f32x4 w3r[32];
    #pragma unroll
    for (int q = 0; q < 32; ++q)
        w3r[q] = *(const f32x4*)(ws + WSU_W3 + (q * 64 + lane) * 8);
    #pragma unroll
    for (int hf = 0; hf < 8; ++hf) asm volatile("" : "+v"(wpf[hf]));
    #pragma unroll
    for (int q = 0; q < 32; ++q)  asm volatile("" : "+v"(w3r[q]));
    __syncthreads();

    const _Float16* sT  = sTU;
    const _Float16* sU  = sTU + WSU_U;
    const unsigned char* viB = (const unsigned char*)(wsb + WSB_VI);
    const unsigned char* vjB = (const unsigned char*)(wsb + WSB_VJ);

    const int ntiles = N_EDGES / 64;            // 15625, 64 edges per block-tile (16/wave)
    const int gstep  = (int)gridDim.x;

    int tile = blockIdx.x;
    if (tile >= ntiles) return;

    // ---- prefetch first tile ----
    f32x4 p0 = {0,0,0,0}, p1 = {0,0,0,0};
    unsigned int viq, vjq;
    {
        int e0 = tile * 64 + w * 16;
        if (g < 2) {
            const float* pr = pair_basis + (size_t)(e0 + m) * 16 + g * 8;
            p0 = *(const f32x4*)pr; p1 = *(const f32x4*)(pr + 4);
        }
        viq = *(const unsigned int*)(viB + e0 + 4 * g);
        vjq = *(const unsigned int*)(vjB + e0 + 4 * g);
    }

    while (true) {
        const int e0 = tile * 64 + w * 16;
        const int nt = tile + gstep;

        // ---- issue next tile's global loads early (hide HBM latency under compute) ----
        f32x4 q0 = {0,0,0,0}, q1 = {0,0,0,0};
        unsigned int nvi = 0, nvj = 0;
        if (nt < ntiles) {
            int ne0 = nt * 64 + w * 16;
            if (g < 2) {
                const float* pr = pair_basis + (size_t)(ne0 + m) * 16 + g * 8;
                q0 = *(const f32x4*)pr; q1 = *(const f32x4*)(pr + 4);
            }
            nvi = *(const unsigned int*)(viB + ne0 + 4 * g);
            nvj = *(const unsigned int*)(vjB + ne0 + 4 * g);
        }

        // ---- B2 frag: pair^T (lane (m,g) supplies pair[e0+m][8g..8g+7]; k=16 row == 1 bias)
        f16x8 b2 = {0, 0, 0, 0, 0, 0, 0, 0};
        if (g < 2) {
            b2[0] = (_Float16)p0[0]; b2[1] = (_Float16)p0[1];
            b2[2] = (_Float16)p0[2]; b2[3] = (_Float16)p0[3];
            b2[4] = (_Float16)p1[0]; b2[5] = (_Float16)p1[1];
            b2[6] = (_Float16)p1[2]; b2[7] = (_Float16)p1[3];
        } else if (g == 2) {
            b2[0] = (_Float16)1.0f;
        }

        // ---- swapped pair GEMM -> silu -> main-GEMM A-frags (all registers) ----
        f16x8 a2[4];
        const f32x4 zero = {0.f, 0.f, 0.f, 0.f};
        #pragma unroll
        for (int ks = 0; ks < 4; ++ks) {
            f32x4 dA = __builtin_amdgcn_mfma_f32_16x16x32_f16(as_f16x8(wpf[2 * ks]),     b2, zero, 0, 0, 0);
            f32x4 dB = __builtin_amdgcn_mfma_f32_16x16x32_f16(as_f16x8(wpf[2 * ks + 1]), b2, zero, 0, 0, 0);
            f16x8 t2;
            #pragma unroll
            for (int r = 0; r < 4; ++r) {
                t2[r]     = (_Float16)silu_f(dA[r]);
                t2[4 + r] = (_Float16)silu_f(dB[r]);
            }
            a2[ks] = t2;
        }

        // ---- C init: T[vi] + U[vj] (b_emb folded into T), vec8 LDS reads ----
        f32x4 acc[8];
        #pragma unroll
        for (int r = 0; r < 4; ++r) {
            int vi = (viq >> (8 * r)) & 0xff;
            int vj = (vjq >> (8 * r)) & 0xff;
            f16x8 tv = *(const f16x8*)(sT + vi * HID + 8 * m);
            f16x8 uv = *(const f16x8*)(sU + vj * HID + 8 * m);
            #pragma unroll
            for (int nf = 0; nf < 8; ++nf)
                acc[nf][r] = (float)tv[nf] + (float)uv[nf];
        }

        // ---- main GEMM: acc += pb @ W3 (pinned register B-frags) ----
        #pragma unroll
        for (int ks = 0; ks < 4; ++ks) {
            #pragma unroll
            for (int nf = 0; nf < 8; ++nf)
                acc[nf] = __builtin_amdgcn_mfma_f32_16x16x32_f16(a2[ks], as_f16x8(w3r[ks * 8 + nf]), acc[nf], 0, 0, 0);
        }

        // ---- epilogue: silu + contiguous float4 stores (cols 8m..8m+7 per thread) ----
        #pragma unroll
        for (int r = 0; r < 4; ++r) {
            float* op = out + (size_t)(e0 + 4 * g + r) * HID + 8 * m;
            f32x4 o0, o1;
            #pragma unroll
            for (int nf = 0; nf < 4; ++nf) {
                o0[nf] = silu_f(acc[nf][r]);
                o1[nf] = silu_f(acc[4 + nf][r]);
            }
            *(f32x4*)op       = o0;
            *(f32x4*)(op + 4) = o1;
        }

        if (nt >= ntiles) break;
        tile = nt; p0 = q0; p1 = q1; viq = nvi; vjq = nvj;
    }
}

extern "C" void kernel_launch(void* const* d_in, const int* in_sizes, int n_in,
                              void* d_out, int out_size, void* d_ws, size_t ws_size,
                              hipStream_t stream) {
    const int*   x          = (const int*)d_in[0];
    const float* pair_basis = (const float*)d_in[1];
    const int*   ii         = (const int*)d_in[2];
    const int*   jj         = (const int*)d_in[3];
    const float* emb_table  = (const float*)d_in[4];
    const float* W_pair     = (const float*)d_in[5];
    const float* b_pair     = (const float*)d_in[6];
    const float* W_emb      = (const float*)d_in[7];
    const float* b_emb      = (const float*)d_in[8];
    char* wsb = (char*)d_ws;
    float* out = (float*)d_out;

    const int ngather = (N_EDGES + 1023) / 1024;              // 977 blocks, 4 edges/thread
    prep_kernel<<<VOC + 64 + 16 + ngather, 256, 0, stream>>>(
        x, ii, jj, emb_table, W_pair, b_pair, W_emb, b_emb, wsb);
    edge_kernel<<<512, 256, 0, stream>>>(pair_basis, wsb, out);
}

// Round 6
// 182.736 us; speedup vs baseline: 1.8972x; 1.1387x over previous
//
#include <hip/hip_runtime.h>
#include <hip/hip_bf16.h>

#define N_EDGES 1000000
#define HID 128
#define VOC 105

// ws layout (fp16 element offsets)
#define WSU_T   0                     // [105][128] T = emb@W_emb[0:128] + b_emb (permuted cols)
#define WSU_U   (VOC * HID)           // 13440 : [105][128] U = emb@W_emb[128:256]
#define WSU_W3  (2 * VOC * HID)       // 26880 : W3 B-frags, 16384 elems
#define WSU_WP  (WSU_W3 + 16384)      // 43264 : W_pair A-frags (swapped gemm), 4096 elems
#define WSU_TU  (2 * VOC * HID)       // T+U contiguous span (elems) = 26880
#define WSB_VI  ((WSU_WP + 4096) * 2) // byte offset 94720 : u8 vi[N_EDGES]
#define WSB_VJ  (WSB_VI + N_EDGES)    // u8 vj[N_EDGES]

typedef float    f32x4 __attribute__((ext_vector_type(4)));
typedef _Float16 f16x8 __attribute__((ext_vector_type(8)));
typedef __fp16   hf2   __attribute__((ext_vector_type(2)));   // cvt_pkrtz native type

static __device__ __forceinline__ f16x8 as_f16x8(f32x4 v) {
    return __builtin_bit_cast(f16x8, v);
}
// packed f32x2 -> f16x2 (single v_cvt_pkrtz_f16_f32)
static __device__ __forceinline__ unsigned int pk2(float a, float b) {
    return __builtin_bit_cast(unsigned int, __builtin_amdgcn_cvt_pkrtz(a, b));
}

// ---------------- prep: tables + pre-packed fragments + vocab pre-gather ----------------
__global__ void prep_kernel(const int*   __restrict__ xv,
                            const int*   __restrict__ ii,
                            const int*   __restrict__ jj,
                            const float* __restrict__ emb_table,
                            const float* __restrict__ W_pair,
                            const float* __restrict__ b_pair,
                            const float* __restrict__ W_emb,
                            const float* __restrict__ b_emb,
                            char* __restrict__ wsb) {
    _Float16* ws = (_Float16*)wsb;
    int b = blockIdx.x, t = threadIdx.x;
    if (b < VOC) {
        // T[v][h] = emb[v]@W_emb[0:128,h] + b_emb[h];  U[v][h] = emb[v]@W_emb[128:256,h]
        int v = b, which = t >> 7, h = t & 127;
        const float* wr = W_emb + which * HID * HID;
        const float* ev = emb_table + v * HID;
        float acc = which ? 0.f : b_emb[h];
        for (int d = 0; d < HID; ++d) acc = fmaf(ev[d], wr[d * HID + h], acc);
        ws[(which ? WSU_U : WSU_T) + v * HID + h] = (_Float16)acc;
    } else if (b < VOC + 64) {
        // W3 B-frags with K-permutation (matches swapped-pair-GEMM output) and
        // N-permutation h_out(nf,c)=8c+nf.  idx = q*512 + lane*8 + t, q = ks*8+nf
        int idx = (b - VOC) * 256 + t;            // 0..16383
        int tt = idx & 7, lane = (idx >> 3) & 63, q = idx >> 9;
        int ks = q >> 3, nf = q & 7;
        int hl = 16 * (tt >> 2) + 4 * (lane >> 4) + (tt & 3);   // logical k within 32-block
        int k = 32 * ks + hl;
        int n = 8 * (lane & 15) + nf;                            // permuted out col
        ws[WSU_W3 + idx] = (_Float16)W_emb[(2 * HID + k) * HID + n];
    } else if (b < VOC + 64 + 16) {
        // W_pair^T A-frags (A2[h][k] = W_pair[k][h]), bias b_pair folded at k==16
        int idx = (b - VOC - 64) * 256 + t;       // 0..4095
        int tt = idx & 7, lane = (idx >> 3) & 63, hf = idx >> 9;
        int k = 8 * (lane >> 4) + tt;
        int h = 16 * hf + (lane & 15);
        float v = (k < 16) ? W_pair[k * HID + h] : (k == 16 ? b_pair[h] : 0.f);
        ws[WSU_WP + idx] = (_Float16)v;
    } else {
        // vocab pre-gather: vi[e] = x[i[e]], vj[e] = x[j[e]] as bytes (VOC=105<256)
        int e4 = ((b - VOC - 64 - 16) * 256 + t) * 4;
        if (e4 < N_EDGES) {
            int4 iv = *(const int4*)(ii + e4);
            int4 jv = *(const int4*)(jj + e4);
            unsigned int vi = (unsigned)xv[iv.x] | ((unsigned)xv[iv.y] << 8) |
                              ((unsigned)xv[iv.z] << 16) | ((unsigned)xv[iv.w] << 24);
            unsigned int vj = (unsigned)xv[jv.x] | ((unsigned)xv[jv.y] << 8) |
                              ((unsigned)xv[jv.z] << 16) | ((unsigned)xv[jv.w] << 24);
            *(unsigned int*)(wsb + WSB_VI + e4) = vi;
            *(unsigned int*)(wsb + WSB_VJ + e4) = vj;
        }
    }
}

// fast silu: 2 trans + 3 VALU (vs ~12-op IEEE div sequence without fast-math)
__device__ __forceinline__ float silu_f(float x) {
    return x * __builtin_amdgcn_rcpf(1.f + __builtin_amdgcn_exp2f(-1.44269504088896341f * x));
}

// ---------------- main: asm-pinned W3/WP in registers, T/U in LDS ----------------
__global__ __launch_bounds__(256, 2) void edge_kernel(
    const float* __restrict__ pair_basis,
    const char*  __restrict__ wsb,
    float* __restrict__ out)
{
    __shared__ __align__(16) _Float16 sTU[WSU_TU];   // T,U : 53760 B
    const _Float16* ws = (const _Float16*)wsb;
    const int tid = threadIdx.x;
    {   // stage T/U into LDS
        const uint4* src = (const uint4*)ws;
        uint4* dst = (uint4*)sTU;
        for (int c = tid; c < (WSU_TU * 2 / 16); c += 256) dst[c] = src[c];
    }
    const int lane = tid & 63;
    const int w    = tid >> 6;     // wave 0..3
    const int m    = lane & 15;
    const int g    = lane >> 4;

    // loop-invariant operands, PINNED in registers via opaque asm (compiler
    // rematerialized these in-loop at VGPR=84 in R3 -> 775 MB HBM re-fetch)
    f32x4 wpf[8];
    #pragma unroll
    for (int hf = 0; hf < 8; ++hf)
        wpf[hf] = *(const f32x4*)(ws + WSU_WP + (hf * 64 + lane) * 8);
    f32x4 w3r[32];
    #pragma unroll
    for (int q = 0; q < 32; ++q)
        w3r[q] = *(const f32x4*)(ws + WSU_W3 + (q * 64 + lane) * 8);
    #pragma unroll
    for (int hf = 0; hf < 8; ++hf) asm volatile("" : "+v"(wpf[hf]));
    #pragma unroll
    for (int q = 0; q < 32; ++q)  asm volatile("" : "+v"(w3r[q]));
    __syncthreads();

    const _Float16* sT  = sTU;
    const _Float16* sU  = sTU + WSU_U;
    const unsigned char* viB = (const unsigned char*)(wsb + WSB_VI);
    const unsigned char* vjB = (const unsigned char*)(wsb + WSB_VJ);

    const int ntiles = N_EDGES / 64;            // 15625, 64 edges per block-tile (16/wave)
    const int gstep  = (int)gridDim.x;

    int tile = blockIdx.x;
    if (tile >= ntiles) return;

    // ---- prefetch first tile ----
    f32x4 p0 = {0,0,0,0}, p1 = {0,0,0,0};
    unsigned int viq, vjq;
    {
        int e0 = tile * 64 + w * 16;
        if (g < 2) {
            const float* pr = pair_basis + (size_t)(e0 + m) * 16 + g * 8;
            p0 = *(const f32x4*)pr; p1 = *(const f32x4*)(pr + 4);
        }
        viq = *(const unsigned int*)(viB + e0 + 4 * g);
        vjq = *(const unsigned int*)(vjB + e0 + 4 * g);
    }

    while (true) {
        const int e0 = tile * 64 + w * 16;
        const int nt = tile + gstep;

        // ---- issue next tile's global loads early (hide HBM latency under compute) ----
        f32x4 q0 = {0,0,0,0}, q1 = {0,0,0,0};
        unsigned int nvi = 0, nvj = 0;
        if (nt < ntiles) {
            int ne0 = nt * 64 + w * 16;
            if (g < 2) {
                const float* pr = pair_basis + (size_t)(ne0 + m) * 16 + g * 8;
                q0 = *(const f32x4*)pr; q1 = *(const f32x4*)(pr + 4);
            }
            nvi = *(const unsigned int*)(viB + ne0 + 4 * g);
            nvj = *(const unsigned int*)(vjB + ne0 + 4 * g);
        }

        // ---- B2 frag: pair^T, packed f32->f16 via cvt_pkrtz ----
        f16x8 b2 = {0, 0, 0, 0, 0, 0, 0, 0};
        if (g < 2) {
            unsigned int u0 = pk2(p0[0], p0[1]);
            unsigned int u1 = pk2(p0[2], p0[3]);
            unsigned int u2 = pk2(p1[0], p1[1]);
            unsigned int u3 = pk2(p1[2], p1[3]);
            uint4 packed = {u0, u1, u2, u3};
            b2 = __builtin_bit_cast(f16x8, packed);
        } else if (g == 2) {
            b2[0] = (_Float16)1.0f;
        }

        // ---- swapped pair GEMM -> fast silu -> packed A-frags (all registers) ----
        f16x8 a2[4];
        const f32x4 zero = {0.f, 0.f, 0.f, 0.f};
        #pragma unroll
        for (int ks = 0; ks < 4; ++ks) {
            f32x4 dA = __builtin_amdgcn_mfma_f32_16x16x32_f16(as_f16x8(wpf[2 * ks]),     b2, zero, 0, 0, 0);
            f32x4 dB = __builtin_amdgcn_mfma_f32_16x16x32_f16(as_f16x8(wpf[2 * ks + 1]), b2, zero, 0, 0, 0);
            uint4 packed;
            packed.x = pk2(silu_f(dA[0]), silu_f(dA[1]));
            packed.y = pk2(silu_f(dA[2]), silu_f(dA[3]));
            packed.z = pk2(silu_f(dB[0]), silu_f(dB[1]));
            packed.w = pk2(silu_f(dB[2]), silu_f(dB[3]));
            a2[ks] = __builtin_bit_cast(f16x8, packed);
        }

        // ---- C init: T[vi] + U[vj] via packed f16 add, then widen ----
        f32x4 acc[8];
        #pragma unroll
        for (int r = 0; r < 4; ++r) {
            int vi = (viq >> (8 * r)) & 0xff;
            int vj = (vjq >> (8 * r)) & 0xff;
            f16x8 tv = *(const f16x8*)(sT + vi * HID + 8 * m);
            f16x8 uv = *(const f16x8*)(sU + vj * HID + 8 * m);
            f16x8 s8 = tv + uv;                      // v_pk_add_f16 x4
            #pragma unroll
            for (int nf = 0; nf < 8; ++nf)
                acc[nf][r] = (float)s8[nf];
        }

        // ---- main GEMM: acc += pb @ W3 (pinned register B-frags) ----
        #pragma unroll
        for (int ks = 0; ks < 4; ++ks) {
            #pragma unroll
            for (int nf = 0; nf < 8; ++nf)
                acc[nf] = __builtin_amdgcn_mfma_f32_16x16x32_f16(a2[ks], as_f16x8(w3r[ks * 8 + nf]), acc[nf], 0, 0, 0);
        }

        // ---- epilogue: fast silu + contiguous float4 stores ----
        #pragma unroll
        for (int r = 0; r < 4; ++r) {
            float* op = out + (size_t)(e0 + 4 * g + r) * HID + 8 * m;
            f32x4 o0, o1;
            #pragma unroll
            for (int nf = 0; nf < 4; ++nf) {
                o0[nf] = silu_f(acc[nf][r]);
                o1[nf] = silu_f(acc[4 + nf][r]);
            }
            *(f32x4*)op       = o0;
            *(f32x4*)(op + 4) = o1;
        }

        if (nt >= ntiles) break;
        tile = nt; p0 = q0; p1 = q1; viq = nvi; vjq = nvj;
    }
}

extern "C" void kernel_launch(void* const* d_in, const int* in_sizes, int n_in,
                              void* d_out, int out_size, void* d_ws, size_t ws_size,
                              hipStream_t stream) {
    const int*   x          = (const int*)d_in[0];
    const float* pair_basis = (const float*)d_in[1];
    const int*   ii         = (const int*)d_in[2];
    const int*   jj         = (const int*)d_in[3];
    const float* emb_table  = (const float*)d_in[4];
    const float* W_pair     = (const float*)d_in[5];
    const float* b_pair     = (const float*)d_in[6];
    const float* W_emb      = (const float*)d_in[7];
    const float* b_emb      = (const float*)d_in[8];
    char* wsb = (char*)d_ws;
    float* out = (float*)d_out;

    const int ngather = (N_EDGES + 1023) / 1024;              // 977 blocks, 4 edges/thread
    prep_kernel<<<VOC + 64 + 16 + ngather, 256, 0, stream>>>(
        x, ii, jj, emb_table, W_pair, b_pair, W_emb, b_emb, wsb);
    edge_kernel<<<512, 256, 0, stream>>>(pair_basis, wsb, out);
}

// Round 7
// 147.945 us; speedup vs baseline: 2.3433x; 1.2352x over previous
//
#include <hip/hip_runtime.h>
#include <hip/hip_bf16.h>

#define N_EDGES 1000000
#define HID 128
#define VOC 105

// ws layout (fp16 element offsets)
#define WSU_T   0                     // [105][128] T = emb@W_emb[0:128] + b_emb (plain cols)
#define WSU_U   (VOC * HID)           // 13440 : [105][128] U = emb@W_emb[128:256]
#define WSU_W3  (2 * VOC * HID)       // 26880 : W3 B-frags, 16384 elems
#define WSU_WP  (WSU_W3 + 16384)      // 43264 : W_pair A-frags (swapped gemm), 4096 elems
#define WSU_TU  (2 * VOC * HID)       // T+U contiguous span (elems) = 26880
#define WSB_VI  ((WSU_WP + 4096) * 2) // byte offset 94720 : u8 vi[N_EDGES]
#define WSB_VJ  (WSB_VI + N_EDGES)    // u8 vj[N_EDGES]

typedef float    f32x4 __attribute__((ext_vector_type(4)));
typedef _Float16 f16x8 __attribute__((ext_vector_type(8)));
typedef _Float16 f16x4 __attribute__((ext_vector_type(4)));

static __device__ __forceinline__ f16x8 as_f16x8(f32x4 v) {
    return __builtin_bit_cast(f16x8, v);
}
// packed f32x2 -> f16x2 (single v_cvt_pkrtz_f16_f32)
static __device__ __forceinline__ unsigned int pk2(float a, float b) {
    return __builtin_bit_cast(unsigned int, __builtin_amdgcn_cvt_pkrtz(a, b));
}

// ---------------- prep: tables + pre-packed fragments + vocab pre-gather ----------------
__global__ void prep_kernel(const int*   __restrict__ xv,
                            const int*   __restrict__ ii,
                            const int*   __restrict__ jj,
                            const float* __restrict__ emb_table,
                            const float* __restrict__ W_pair,
                            const float* __restrict__ b_pair,
                            const float* __restrict__ W_emb,
                            const float* __restrict__ b_emb,
                            char* __restrict__ wsb) {
    _Float16* ws = (_Float16*)wsb;
    int b = blockIdx.x, t = threadIdx.x;
    if (b < VOC) {
        // T[v][h] = emb[v]@W_emb[0:128,h] + b_emb[h];  U[v][h] = emb[v]@W_emb[128:256,h]
        int v = b, which = t >> 7, h = t & 127;
        const float* wr = W_emb + which * HID * HID;
        const float* ev = emb_table + v * HID;
        float acc = which ? 0.f : b_emb[h];
        for (int d = 0; d < HID; ++d) acc = fmaf(ev[d], wr[d * HID + h], acc);
        ws[(which ? WSU_U : WSU_T) + v * HID + h] = (_Float16)acc;
    } else if (b < VOC + 64) {
        // W3 B-frags: K-perm matches swapped-pair-GEMM output; N-perm gives DENSE stores:
        // h_out(nf,p) = 4p+nf (nf<4) | 64+4p+(nf-4)  -> each thread owns 2 dense float4 cols
        int idx = (b - VOC) * 256 + t;            // 0..16383
        int tt = idx & 7, lane = (idx >> 3) & 63, q = idx >> 9;
        int ks = q >> 3, nf = q & 7;
        int hl = 16 * (tt >> 2) + 4 * (lane >> 4) + (tt & 3);   // logical k within 32-block
        int k = 32 * ks + hl;
        int p = lane & 15;
        int n = (nf < 4) ? (4 * p + nf) : (64 + 4 * p + (nf - 4));  // dense-store N-perm
        ws[WSU_W3 + idx] = (_Float16)W_emb[(2 * HID + k) * HID + n];
    } else if (b < VOC + 64 + 16) {
        // W_pair^T A-frags (A2[h][k] = W_pair[k][h]), bias b_pair folded at k==16
        int idx = (b - VOC - 64) * 256 + t;       // 0..4095
        int tt = idx & 7, lane = (idx >> 3) & 63, hf = idx >> 9;
        int k = 8 * (lane >> 4) + tt;
        int h = 16 * hf + (lane & 15);
        float v = (k < 16) ? W_pair[k * HID + h] : (k == 16 ? b_pair[h] : 0.f);
        ws[WSU_WP + idx] = (_Float16)v;
    } else {
        // vocab pre-gather: vi[e] = x[i[e]], vj[e] = x[j[e]] as bytes (VOC=105<256)
        int e4 = ((b - VOC - 64 - 16) * 256 + t) * 4;
        if (e4 < N_EDGES) {
            int4 iv = *(const int4*)(ii + e4);
            int4 jv = *(const int4*)(jj + e4);
            unsigned int vi = (unsigned)xv[iv.x] | ((unsigned)xv[iv.y] << 8) |
                              ((unsigned)xv[iv.z] << 16) | ((unsigned)xv[iv.w] << 24);
            unsigned int vj = (unsigned)xv[jv.x] | ((unsigned)xv[jv.y] << 8) |
                              ((unsigned)xv[jv.z] << 16) | ((unsigned)xv[jv.w] << 24);
            *(unsigned int*)(wsb + WSB_VI + e4) = vi;
            *(unsigned int*)(wsb + WSB_VJ + e4) = vj;
        }
    }
}

// fast silu: 2 trans + 3 VALU
__device__ __forceinline__ float silu_f(float x) {
    return x * __builtin_amdgcn_rcpf(1.f + __builtin_amdgcn_exp2f(-1.44269504088896341f * x));
}

// ---------------- main: asm-pinned W3/WP in regs, T/U in LDS, dense NT stores ----------------
__global__ __launch_bounds__(256, 2) void edge_kernel(
    const float* __restrict__ pair_basis,
    const char*  __restrict__ wsb,
    float* __restrict__ out)
{
    __shared__ __align__(16) _Float16 sTU[WSU_TU];   // T,U : 53760 B
    const _Float16* ws = (const _Float16*)wsb;
    const int tid = threadIdx.x;
    {   // stage T/U into LDS
        const uint4* src = (const uint4*)ws;
        uint4* dst = (uint4*)sTU;
        for (int c = tid; c < (WSU_TU * 2 / 16); c += 256) dst[c] = src[c];
    }
    const int lane = tid & 63;
    const int w    = tid >> 6;     // wave 0..3
    const int m    = lane & 15;    // p: MFMA col index
    const int g    = lane >> 4;

    // loop-invariant operands, PINNED via opaque asm (R3: without pins the compiler
    // rematerialized these in-loop at VGPR=84 -> 775 MB HBM re-fetch)
    f32x4 wpf[8];
    #pragma unroll
    for (int hf = 0; hf < 8; ++hf)
        wpf[hf] = *(const f32x4*)(ws + WSU_WP + (hf * 64 + lane) * 8);
    f32x4 w3r[32];
    #pragma unroll
    for (int q = 0; q < 32; ++q)
        w3r[q] = *(const f32x4*)(ws + WSU_W3 + (q * 64 + lane) * 8);
    #pragma unroll
    for (int hf = 0; hf < 8; ++hf) asm volatile("" : "+v"(wpf[hf]));
    #pragma unroll
    for (int q = 0; q < 32; ++q)  asm volatile("" : "+v"(w3r[q]));
    __syncthreads();

    const _Float16* sT  = sTU;
    const _Float16* sU  = sTU + WSU_U;
    const unsigned char* viB = (const unsigned char*)(wsb + WSB_VI);
    const unsigned char* vjB = (const unsigned char*)(wsb + WSB_VJ);

    const int ntiles = N_EDGES / 64;            // 15625, 64 edges per block-tile (16/wave)
    const int gstep  = (int)gridDim.x;

    int tile = blockIdx.x;
    if (tile >= ntiles) return;

    // ---- prefetch first tile (pair: nontemporal, read-once stream) ----
    f32x4 p0 = {0,0,0,0}, p1 = {0,0,0,0};
    unsigned int viq, vjq;
    {
        int e0 = tile * 64 + w * 16;
        if (g < 2) {
            const f32x4* pr = (const f32x4*)(pair_basis + (size_t)(e0 + m) * 16 + g * 8);
            p0 = __builtin_nontemporal_load(pr);
            p1 = __builtin_nontemporal_load(pr + 1);
        }
        viq = *(const unsigned int*)(viB + e0 + 4 * g);
        vjq = *(const unsigned int*)(vjB + e0 + 4 * g);
    }

    while (true) {
        const int e0 = tile * 64 + w * 16;
        const int nt = tile + gstep;

        // ---- issue next tile's global loads early ----
        f32x4 q0 = {0,0,0,0}, q1 = {0,0,0,0};
        unsigned int nvi = 0, nvj = 0;
        if (nt < ntiles) {
            int ne0 = nt * 64 + w * 16;
            if (g < 2) {
                const f32x4* pr = (const f32x4*)(pair_basis + (size_t)(ne0 + m) * 16 + g * 8);
                q0 = __builtin_nontemporal_load(pr);
                q1 = __builtin_nontemporal_load(pr + 1);
            }
            nvi = *(const unsigned int*)(viB + ne0 + 4 * g);
            nvj = *(const unsigned int*)(vjB + ne0 + 4 * g);
        }

        // ---- B2 frag: pair^T, packed f32->f16 ----
        f16x8 b2 = {0, 0, 0, 0, 0, 0, 0, 0};
        if (g < 2) {
            uint4 packed = {pk2(p0[0], p0[1]), pk2(p0[2], p0[3]),
                            pk2(p1[0], p1[1]), pk2(p1[2], p1[3])};
            b2 = __builtin_bit_cast(f16x8, packed);
        } else if (g == 2) {
            b2[0] = (_Float16)1.0f;   // bias row k==16
        }

        // ---- swapped pair GEMM -> fast silu -> packed A-frags (all registers) ----
        f16x8 a2[4];
        const f32x4 zero = {0.f, 0.f, 0.f, 0.f};
        #pragma unroll
        for (int ks = 0; ks < 4; ++ks) {
            f32x4 dA = __builtin_amdgcn_mfma_f32_16x16x32_f16(as_f16x8(wpf[2 * ks]),     b2, zero, 0, 0, 0);
            f32x4 dB = __builtin_amdgcn_mfma_f32_16x16x32_f16(as_f16x8(wpf[2 * ks + 1]), b2, zero, 0, 0, 0);
            uint4 packed;
            packed.x = pk2(silu_f(dA[0]), silu_f(dA[1]));
            packed.y = pk2(silu_f(dA[2]), silu_f(dA[3]));
            packed.z = pk2(silu_f(dB[0]), silu_f(dB[1]));
            packed.w = pk2(silu_f(dB[2]), silu_f(dB[3]));
            a2[ks] = __builtin_bit_cast(f16x8, packed);
        }

        // ---- C init: T[vi] + U[vj], split b64 reads (cols 4m..4m+3 and 64+4m..+3) ----
        f32x4 acc[8];
        #pragma unroll
        for (int r = 0; r < 4; ++r) {
            int vi = (viq >> (8 * r)) & 0xff;
            int vj = (vjq >> (8 * r)) & 0xff;
            f16x4 tlo = *(const f16x4*)(sT + vi * HID + 4 * m);
            f16x4 thi = *(const f16x4*)(sT + vi * HID + 64 + 4 * m);
            f16x4 ulo = *(const f16x4*)(sU + vj * HID + 4 * m);
            f16x4 uhi = *(const f16x4*)(sU + vj * HID + 64 + 4 * m);
            f16x4 slo = tlo + ulo;                   // v_pk_add_f16 x2
            f16x4 shi = thi + uhi;
            #pragma unroll
            for (int nf = 0; nf < 4; ++nf) {
                acc[nf][r]     = (float)slo[nf];
                acc[4 + nf][r] = (float)shi[nf];
            }
        }

        // ---- main GEMM: acc += pb @ W3 (pinned register B-frags) ----
        #pragma unroll
        for (int ks = 0; ks < 4; ++ks) {
            #pragma unroll
            for (int nf = 0; nf < 8; ++nf)
                acc[nf] = __builtin_amdgcn_mfma_f32_16x16x32_f16(a2[ks], as_f16x8(w3r[ks * 8 + nf]), acc[nf], 0, 0, 0);
        }

        // ---- epilogue: fast silu + DENSE nontemporal float4 stores ----
        // thread (m,g) r: cols 4m..4m+3 and 64+4m..64+4m+3 -> 16 lanes = 256B contiguous
        #pragma unroll
        for (int r = 0; r < 4; ++r) {
            float* op = out + (size_t)(e0 + 4 * g + r) * HID + 4 * m;
            f32x4 o0, o1;
            #pragma unroll
            for (int nf = 0; nf < 4; ++nf) {
                o0[nf] = silu_f(acc[nf][r]);
                o1[nf] = silu_f(acc[4 + nf][r]);
            }
            __builtin_nontemporal_store(o0, (f32x4*)op);
            __builtin_nontemporal_store(o1, (f32x4*)(op + 64));
        }

        if (nt >= ntiles) break;
        tile = nt; p0 = q0; p1 = q1; viq = nvi; vjq = nvj;
    }
}

extern "C" void kernel_launch(void* const* d_in, const int* in_sizes, int n_in,
                              void* d_out, int out_size, void* d_ws, size_t ws_size,
                              hipStream_t stream) {
    const int*   x          = (const int*)d_in[0];
    const float* pair_basis = (const float*)d_in[1];
    const int*   ii         = (const int*)d_in[2];
    const int*   jj         = (const int*)d_in[3];
    const float* emb_table  = (const float*)d_in[4];
    const float* W_pair     = (const float*)d_in[5];
    const float* b_pair     = (const float*)d_in[6];
    const float* W_emb      = (const float*)d_in[7];
    const float* b_emb      = (const float*)d_in[8];
    char* wsb = (char*)d_ws;
    float* out = (float*)d_out;

    const int ngather = (N_EDGES + 1023) / 1024;              // 977 blocks, 4 edges/thread
    prep_kernel<<<VOC + 64 + 16 + ngather, 256, 0, stream>>>(
        x, ii, jj, emb_table, W_pair, b_pair, W_emb, b_emb, wsb);
    edge_kernel<<<512, 256, 0, stream>>>(pair_basis, wsb, out);
}